// Round 2
// 257.875 us; speedup vs baseline: 1.0322x; 1.0322x over previous
//
#include <hip/hip_runtime.h>

// ---- problem constants (reference setup_inputs) ----
#define BATCH  128
#define NPTS   4000
#define NA     400
#define BN     (BATCH * NPTS)

// ---- wave-independent decomposition ----
// 20 waves per row; each wave owns 200 cells + 28-cell halo each side:
// 256 local cells = 4 per lane, exact fit. Halo 28 > 25 steps -> owned region
// never contaminated by the lane-edge self-clamp. NO __syncthreads anywhere;
// neighbor exchange is intra-wave __shfl. 4 launches x 25 steps.
// 2560 single-wave blocks = 10/CU = 2.5 waves/SIMD (was 1.25 -> latency-bound).
#define CHUNKS 20
#define OWN    (NPTS / CHUNKS)   // 200
#define HALO   28
#define CPL    4                 // cells per lane (64*4 = 256 = OWN + 2*HALO)
#define SSTEPS 25
#define NLAUNCH 4

// fh(u) = 0.5*f(u) = 0.25u(3-u^2) + 12.5u^2(0.75 - 2u + 1.5u^2 - 0.25u^4)
// (0.5 folded into coefficients; exact pow2 scaling of the original constants)
__device__ __forceinline__ float fh_of(float u) {
    float u2 = u * u;
    float p  = fmaf(u2, fmaf(u2, -0.25f, 1.5f), fmaf(u, -2.0f, 0.75f));
    return fmaf(12.5f * u2, p, u * fmaf(u2, -0.25f, 0.75f));
}

// gh(u) = 0.5*|f'(u)| = |0.75 + 18.75u - 75.75u^2 + 75u^3 - 18.75u^5|
__device__ __forceinline__ float gh_of(float u) {
    float u2 = u * u;
    return fabsf(fmaf(u, fmaf(u, fmaf(u, fmaf(u2, -18.75f, 75.0f), -75.75f), 18.75f), 0.75f));
}

// A'(u) = A(u)/dx, closed form: piecewise linear, slopes {0, .25, .5}/dx, capped.
// t1 = s1*u + c1 (middle piece), t2 = s2*u + c2 (upper piece); max with 0, cap.
__device__ __forceinline__ float Ax_of(float u, float s1c, float c1,
                                       float s2c, float c2, float Amaxp) {
    float t1 = fmaf(s1c, u, c1);
    float t2 = fmaf(s2c, u, c2);
    return fminf(fmaxf(fmaxf(t1, t2), 0.0f), Amaxp);
}

__device__ __forceinline__ int iclamp(int v, int lo, int hi) {
    return v < lo ? lo : (v > hi ? hi : v);
}

__global__ __launch_bounds__(64)
void vclin_wave_kernel(const float* __restrict__ src,   // state at step0 (B x N)
                       float* __restrict__ out,          // traj base (101 x B x N)
                       const float* __restrict__ u_a,
                       const float* __restrict__ dtp,
                       const float* __restrict__ dxp,
                       int step0, int write_src) {
    const int lane  = threadIdx.x;            // 0..63 (one wave per block)
    const int w     = blockIdx.x;
    const int row   = w / CHUNKS;
    const int chunk = w - row * CHUNKS;
    const int own_start = chunk * OWN;
    const int gbase = own_start - HALO + CPL * lane;     // global idx of cell 0
    const bool owner = (gbase >= own_start) && (gbase < own_start + OWN);
    const size_t rowbase = (size_t)row * NPTS;

    // ---- locate the 0.5 step in this row's u_a knots (wave-local, no LDS) ----
    const float* ua_row = u_a + (size_t)row * (NA + 1);
    float xlo = 0.0f, xhi = 1.0f;
    bool found = false;
    #pragma unroll
    for (int j = 0; j < 7; ++j) {
        int k = 7 * lane + j;
        if (k < NA) {
            float a = ua_row[k], b = ua_row[k + 1];
            if (a < 0.5f && b >= 0.5f) { xlo = a; xhi = b; found = true; }
        }
    }
    unsigned long long m = __ballot(found);
    int srcLane = (m != 0ull) ? (__ffsll((long long)m) - 1) : 0;
    xlo = __shfl(xlo, srcLane);
    xhi = __shfl(xhi, srcLane);
    const float xmax = ua_row[NA];

    const float DT  = dtp[0];
    const float DX  = dxp[0];
    const float lam = DT / DX;
    const float invdx = 1.0f / DX;
    // A'(u) = invdx * A(u); fold invdx into slopes and caps.
    const float s1c   = 0.25f * invdx;                    // middle slope
    const float s2c   = 0.5f  * invdx;                    // upper slope
    const float Aj0p  = s1c * (xhi - xlo);                // A'(xhi)
    const float c1    = -s1c * xlo;                       // t1 = s1*(u - xlo)
    const float c2    = fmaf(-s2c, xhi, Aj0p);            // t2 = Aj0' + s2*(u - xhi)
    const float Amaxp = fmaf(s2c, xmax - xhi, Aj0p);

    // ---- load 4 local cells (clamped at row ends for virtual cells) ----
    float u[CPL];
    if (gbase >= 0 && gbase + CPL <= NPTS) {
        float4 a = *reinterpret_cast<const float4*>(src + rowbase + gbase);
        u[0] = a.x; u[1] = a.y; u[2] = a.z; u[3] = a.w;
    } else {
        #pragma unroll
        for (int c = 0; c < CPL; ++c)
            u[c] = src[rowbase + iclamp(gbase + c, 0, NPTS - 1)];
    }

    float* wp = nullptr;
    if (owner) {
        wp = out + (size_t)(step0 + 1) * BN + rowbase + gbase;
        if (write_src) {   // first launch also writes trajectory step 0 = init
            float4 a; a.x = u[0]; a.y = u[1]; a.z = u[2]; a.w = u[3];
            *reinterpret_cast<float4*>(out + rowbase + gbase) = a;
        }
    }

    const bool bcL = (gbase == 0);
    const bool bcR = (gbase == NPTS - CPL);

    // pipelined left-edge value: left neighbor's last cell (self-clamp at lane 0
    // corrupts only the halo zone, 1 cell/step inward)
    float lu = __shfl_up(u[CPL - 1], 1);
    if (lane == 0) lu = u[0];

    #pragma unroll 2
    for (int s = 0; s < SSTEPS; ++s) {
        // pointwise own cells (independent of the pipelined shuffle -> hides
        // the ds_bpermute latency from the bottom of the previous iteration)
        float fh[CPL], gh[CPL], Ax[CPL];
        #pragma unroll
        for (int c = 0; c < CPL; ++c) {
            fh[c] = fh_of(u[c]);
            gh[c] = gh_of(u[c]);
            Ax[c] = Ax_of(u[c], s1c, c1, s2c, c2, Amaxp);
        }
        // left ghost recomputed from lu (replaces 3 shuffles with ~19 VALU ops
        // that the scheduler can overlap freely)
        float lfh = fh_of(lu);
        float lgh = gh_of(lu);
        float lA  = Ax_of(lu, s1c, c1, s2c, c2, Amaxp);

        // interface flux F = (fh_l + fh_r) - max(gh_l,gh_r)*(u_r-u_l) - (A'_r - A'_l)
        float F[CPL];
        F[0] = fmaf(-fmaxf(lgh, gh[0]), u[0] - lu, lfh + fh[0]) - (Ax[0] - lA);
        #pragma unroll
        for (int c = 1; c < CPL; ++c)
            F[c] = fmaf(-fmaxf(gh[c - 1], gh[c]), u[c] - u[c - 1], fh[c - 1] + fh[c])
                 - (Ax[c] - Ax[c - 1]);

        // right interface flux == right neighbor's F[0] (identical by
        // construction) -> one shuffle instead of a full right ghost + flux
        float rF = __shfl_down(F[0], 1);
        if (lane == 63) rF = fh[CPL - 1] + fh[CPL - 1];   // mirror: du=0, dA=0

        float nu[CPL];
        #pragma unroll
        for (int c = 0; c < CPL - 1; ++c)
            nu[c] = fmaf(-lam, F[c + 1] - F[c], u[c]);
        nu[CPL - 1] = fmaf(-lam, rF - F[CPL - 1], u[CPL - 1]);

        // true boundary: u[0] = u_new[1]; u[N-1] = u_new[N-2]
        if (bcL) nu[0] = nu[1];
        if (bcR) nu[CPL - 1] = nu[CPL - 2];

        #pragma unroll
        for (int c = 0; c < CPL; ++c) u[c] = nu[c];

        // issue next step's edge shuffle NOW; consumed only after the next
        // iteration's pointwise block -> latency fully hidden
        lu = __shfl_up(u[CPL - 1], 1);
        if (lane == 0) lu = u[0];

        if (owner) {
            float4 a; a.x = u[0]; a.y = u[1]; a.z = u[2]; a.w = u[3];
            *reinterpret_cast<float4*>(wp) = a;
            wp += BN;
        }
    }
}

extern "C" void kernel_launch(void* const* d_in, const int* in_sizes, int n_in,
                              void* d_out, int out_size, void* d_ws, size_t ws_size,
                              hipStream_t stream) {
    const float* init = (const float*)d_in[0];   // (128, 4000)
    const float* u_a  = (const float*)d_in[1];   // (128, 401)
    const float* dt   = (const float*)d_in[2];
    const float* dx   = (const float*)d_in[3];
    float* out = (float*)d_out;                  // (101, 128, 4000) fp32

    const int grid = BATCH * CHUNKS;             // 2560 single-wave blocks

    for (int L = 0; L < NLAUNCH; ++L) {
        const float* s = (L == 0) ? init : (out + (size_t)(L * SSTEPS) * BN);
        hipLaunchKernelGGL(vclin_wave_kernel, dim3(grid), dim3(64), 0, stream,
                           s, out, u_a, dt, dx, L * SSTEPS, (L == 0) ? 1 : 0);
    }
}